// Round 2
// baseline (62.090 us; speedup 1.0000x reference)
//
#include <hip/hip_runtime.h>
#include <math.h>

namespace {

constexpr int NCH   = 32;     // channels
constexpr int NG    = 2048;   // grid points
constexpr int BATCH = 32;
constexpr float DXC = 0.08f;

constexpr int NSEG   = 8;             // output segments per row (blocks per b)
constexpr int SEGLEN = NG / NSEG;     // 256 m-values per block
constexpr int NCHUNK = 32;            // chunks over the full row
constexpr int CHL    = NG / NCHUNK;   // 64 elements per chunk
constexpr int NSUB   = 8;             // subchunks per chunk
constexpr int SUBL   = CHL / NSUB;    // 8 elements per subchunk
constexpr int CPS    = NCHUNK / NSEG; // chunks per segment = 4

// out[b,m,c] = s_c * (F[m] + G[m] - x[m])
//   F[m] = x[m] + r_c F[m-1], G[m] = x[m] + r_c G[m+1]
//   r_c = exp(-DX/w_c), s_c = DX/(2 w_c), w_c = 0.1 + 4.9*sigmoid(eta_c)
// All decay factors come from the LDS power table pw[i][c] = r_c^i.
__global__ __launch_bounds__(1024)
void egc_kernel(const float* __restrict__ inputs,
                const float* __restrict__ eta,
                float* __restrict__ out) {
    __shared__ float xs[NG];                 // 8 KB: full input row
    __shared__ float pw[64][NCH];            // 8 KB: r^i per channel
    __shared__ float F8[CPS][NSUB][NCH];     // 4 KB: local fwd scan @ subchunk ends (own segment)
    __shared__ float G8[CPS][NSUB][NCH];     // 4 KB: local bwd scan @ subchunk starts (own segment)
    __shared__ float Ef[NCHUNK][NCH];        // 4 KB: per-chunk total fwd carry
    __shared__ float Eb[NCHUNK][NCH];        // 4 KB: per-chunk total bwd carry
    __shared__ float CF[NCHUNK][NCH];        // 4 KB: full F entering chunk
    __shared__ float CB[NCHUNK][NCH];        // 4 KB: full G just past chunk end

    const int tid = threadIdx.x;
    const int c   = tid & 31;        // channel (fast index -> conflict-free LDS, coalesced writes)
    const int t   = tid >> 5;        // chunk-thread [0,32)
    const int b   = blockIdx.x >> 3;
    const int seg = blockIdx.x & (NSEG - 1);

    // per-channel parameters
    const float e   = eta[c];
    const float sig = 1.0f / (1.0f + expf(-e));
    const float w   = 0.1f + 4.9f * sig;
    const float lam = DXC / w;
    const float s   = 0.5f * DXC / w;

    // ---- phase 0: stage input row + power table ----
    const float* xrow = inputs + (size_t)b * NG;
    xs[tid]        = xrow[tid];
    xs[tid + 1024] = xrow[tid + 1024];
    pw[t][c]      = expf(-lam * (float)t);        // r^t   (t in [0,32))
    pw[t + 32][c] = expf(-lam * (float)(t + 32)); // r^(t+32)
    __syncthreads();

    // per-thread copies of small powers (broadcast reads, conflict-free)
    float p[SUBL];
#pragma unroll
    for (int i = 0; i < SUBL; ++i) p[i] = pw[i][c];
    const float r  = p[1];
    const float p8 = pw[SUBL][c];                 // r^8

    // ---- phase 1: chunk t sub-totals (8 independent 8-FMA chains per direction) ----
    {
        const int base = t * CHL;
        float sf[NSUB], sb[NSUB];
#pragma unroll
        for (int ss = 0; ss < NSUB; ++ss) {
            const int o = base + ss * SUBL;
            float xv[SUBL];
#pragma unroll
            for (int i = 0; i < SUBL; ++i) xv[i] = xs[o + i];
            float f = 0.0f, g = 0.0f;
#pragma unroll
            for (int i = 0; i < SUBL; ++i) {
                f = fmaf(p[SUBL - 1 - i], xv[i], f);   // sum x[i] * r^(7-i)
                g = fmaf(p[i],            xv[i], g);   // sum x[i] * r^i
            }
            sf[ss] = f; sb[ss] = g;
        }

        // fold sub-totals with r^8: full-chunk carries + (own segment) sub-scans
        const int  tc  = t - seg * CPS;
        const bool own = (tc >= 0) && (tc < CPS);
        float fa = 0.0f;
#pragma unroll
        for (int ss = 0; ss < NSUB; ++ss) {
            fa = fmaf(p8, fa, sf[ss]);
            if (own) F8[tc][ss][c] = fa;
        }
        float ga = 0.0f;
#pragma unroll
        for (int ss = NSUB - 1; ss >= 0; --ss) {
            ga = fmaf(p8, ga, sb[ss]);
            if (own) G8[tc][ss][c] = ga;
        }
        Ef[t][c] = fa;
        Eb[t][c] = ga;
    }
    __syncthreads();

    // ---- phase 2: chunk-level carry scans, prefetched + fully unrolled ----
    {
        const float rho = expf(-lam * (float)CHL);   // r^64
        if (t == 0) {                                // wave 0, lanes 0..31
            float ev[NCHUNK];
#pragma unroll
            for (int k = 0; k < NCHUNK; ++k) ev[k] = Ef[k][c];
            float fe = 0.0f;
#pragma unroll
            for (int k = 0; k < NCHUNK; ++k) { CF[k][c] = fe; fe = fmaf(rho, fe, ev[k]); }
        } else if (t == 2) {                         // wave 1, lanes 0..31
            float ev[NCHUNK];
#pragma unroll
            for (int k = 0; k < NCHUNK; ++k) ev[k] = Eb[k][c];
            float ge = 0.0f;
#pragma unroll
            for (int k = NCHUNK - 1; k >= 0; --k) { CB[k][c] = ge; ge = fmaf(rho, ge, ev[k]); }
        }
    }
    __syncthreads();

    // ---- phase 3: finalize 8 outputs of subchunk T = seg*32 + t ----
    const int T     = seg * (SEGLEN / SUBL) + t;
    const int chunk = T >> 3;
    const int sub   = T & (NSUB - 1);
    const int tc    = chunk - seg * CPS;
    const int m0    = T * SUBL;

    float fin = CF[chunk][c] * pw[SUBL * sub][c];            // carry decayed by 8*sub elems
    if (sub > 0) fin += F8[tc][sub - 1][c];
    float gin;
    if (sub < NSUB - 1)
        gin = G8[tc][sub + 1][c] + CB[chunk][c] * pw[CHL - SUBL * (sub + 1)][c];
    else
        gin = CB[chunk][c];

    float xv[SUBL], Fv[SUBL];
#pragma unroll
    for (int i = 0; i < SUBL; ++i) xv[i] = xs[m0 + i];

    float f = fin;
#pragma unroll
    for (int i = 0; i < SUBL; ++i) { f = fmaf(r, f, xv[i]); Fv[i] = f; }

    float g = gin;
    float* orow = out + ((size_t)b * NG + m0) * NCH + c;
#pragma unroll
    for (int i = SUBL - 1; i >= 0; --i) {
        g = fmaf(r, g, xv[i]);
        orow[(size_t)i * NCH] = s * (Fv[i] + g - xv[i]);
    }
}

} // namespace

extern "C" void kernel_launch(void* const* d_in, const int* in_sizes, int n_in,
                              void* d_out, int out_size, void* d_ws, size_t ws_size,
                              hipStream_t stream) {
    const float* inputs = (const float*)d_in[0];
    // d_in[1] = grids (uniform spacing DX; |x_n - x_m| = |n-m|*DX, so unused)
    const float* eta    = (const float*)d_in[2];
    float* out          = (float*)d_out;

    dim3 grid(BATCH * NSEG);   // 256 blocks: (b, segment)
    dim3 block(1024);          // (32 channels) x (32 chunk-threads)
    hipLaunchKernelGGL(egc_kernel, grid, block, 0, stream, inputs, eta, out);
}